// Round 7
// baseline (36859.415 us; speedup 1.0000x reference)
//
#include <hip/hip_runtime.h>
#include <stdint.h>

typedef __bf16 bf16;
typedef __attribute__((ext_vector_type(8))) __bf16 bf16x8;
typedef __attribute__((ext_vector_type(4))) float f32x4;

// ---------------- workspace layout (bytes), total ~45.1 MB ----------------
#define OFF_W0P   0ull
#define SZ_W0P    10485760ull
#define OFF_W1P   (OFF_W0P + SZ_W0P)
#define SZ_W1P    16777216ull
#define OFF_WOUT  (OFF_W1P + SZ_W1P)
#define SZ_WOUT   524288ull
#define OFF_B0P   (OFF_WOUT + SZ_WOUT)      // f32 permuted b0 [4096]
#define OFF_B1P   (OFF_B0P + 16384ull)      // f32 permuted b1 [4096]
#define OFF_BOP   (OFF_B1P + 16384ull)      // f32 bout [256]
#define OFF_BAR   (OFF_BOP + 1024ull)       // (legacy, unused)
#define OFF_FLAG  (OFF_BAR + 128ull)        // dtype flag: 1 = inputs are f32, 0 = bf16
#define OFF_H0PP  (OFF_BAR + 256ull)        // h0 ping-pong: 2 x 131072 (A-frag packed bf16)
#define OFF_H1PP  (OFF_H0PP + 262144ull)    // h1 ping-pong: 2 x 131072
#define OFF_XP    (OFF_H1PP + 262144ull)    // x repacked: [t 512][mt 4][kt 8][lane 64][8 bf16]
#define SZ_XP     16777216ull
#define OFF_FLAGS (OFF_XP + SZ_XP)          // grid barrier flags: uint[256], monotonic
// end = 45,123,840 bytes

#define OUT_FS0   8388608
#define OUT_FS1   8519680

// LDS map (dynamic, 135424 B)
#define L_A     0        // 4 waves x 3-buffer ring x 8192 (chunk = 2 ktiles x 4 m x 1KB)
#define L_G0    98304    // acc0 partials: [w 4][m 4][lane 64]x16B
#define L_G1    114688
#define L_GP    131072   // accP partials: [w 4][lane 64]x16B
#define L_SYNC  135168   // arr2 @ +0 (pad to 256)
#define LDS_TOT 135424

typedef const __attribute__((address_space(1))) void gvoid_t;
typedef __attribute__((address_space(3))) void lvoid_t;

__device__ __forceinline__ void gl_lds16(void* lds, const void* g) {
  __builtin_amdgcn_global_load_lds((gvoid_t*)g, (lvoid_t*)lds, 16, 0, 0);
}
__device__ __forceinline__ void waitv16() { __asm__ volatile("s_waitcnt vmcnt(16)" ::: "memory"); }
__device__ __forceinline__ void waitv8()  { __asm__ volatile("s_waitcnt vmcnt(8)"  ::: "memory"); }
__device__ __forceinline__ void waitv0()  { __asm__ volatile("s_waitcnt vmcnt(0)"  ::: "memory"); }

__device__ __forceinline__ size_t hpack_off(int b, int u) {
  return (size_t)((((b >> 4) * 32 + (u >> 5)) * 64 + ((b & 15) | (((u >> 3) & 3) << 4))) * 16 + ((u & 7) << 1));
}
__device__ __forceinline__ float sigm(float v) { return 1.0f / (1.0f + __expf(-v)); }
__device__ __forceinline__ float tanh_(float v) { return 2.0f / (1.0f + __expf(-2.0f * v)) - 1.0f; }
__device__ __forceinline__ float scrub(float v, float lim) { return fminf(fmaxf(v, -lim), lim); }
__device__ __forceinline__ float ldel(const void* p, size_t i, int fl) {
  return fl ? ((const float*)p)[i] : (float)((const bf16*)p)[i];
}

// ---------------- dtype detection ----------------
__global__ __launch_bounds__(256) void detect_kernel(const void* __restrict__ W0, char* __restrict__ ws) {
  __shared__ int cnt;
  if (threadIdx.x == 0) cnt = 0;
  __syncthreads();
  int local = 0;
  const unsigned* w = (const unsigned*)W0;
#pragma unroll
  for (int i = 0; i < 4; ++i) {
    unsigned e = (w[threadIdx.x * 4 + i] >> 7) & 0xFF;
    local += (e >= 0x68 && e <= 0x7E) ? 1 : 0;
  }
  atomicAdd(&cnt, local);
  __syncthreads();
  if (threadIdx.x == 0) *(unsigned*)(ws + OFF_FLAG) = (cnt < 512) ? 1u : 0u;
}

// ---------------- weight/x prep (proven round 4) ----------------
__global__ __launch_bounds__(256) void prep_pack(const void* __restrict__ x, const void* __restrict__ W0,
                                                 const void* __restrict__ b0, const void* __restrict__ W1,
                                                 const void* __restrict__ b1, const void* __restrict__ Wout,
                                                 const void* __restrict__ bout, char* __restrict__ ws) {
  const int fl = *(const unsigned*)(ws + OFF_FLAG);
  int id = blockIdx.x * 256 + threadIdx.x;
  if (id < 5242880) {
    int tile = id / 20480, rem = id % 20480;
    int kt = rem >> 9, l = (rem >> 3) & 63, jj = rem & 7;
    int k = kt * 32 + ((l >> 4) << 3) + jj;
    int pc = tile * 16 + (l & 15);
    ((bf16*)(ws + OFF_W0P))[id] = (bf16)ldel(W0, (size_t)k * 4096 + (pc & 3) * 1024 + (pc >> 2), fl);
  } else if (id < 13631488) {
    int id2 = id - 5242880;
    int tile = id2 >> 15, rem = id2 & 32767;
    int kt = rem >> 9, l = (rem >> 3) & 63, jj = rem & 7;
    int k = kt * 32 + ((l >> 4) << 3) + jj;
    int pc = tile * 16 + (l & 15);
    ((bf16*)(ws + OFF_W1P))[id2] = (bf16)ldel(W1, (size_t)k * 4096 + (pc & 3) * 1024 + (pc >> 2), fl);
  } else if (id < 13893632) {
    int id2 = id - 13631488;
    int kt = id2 / 8192, rem = id2 % 8192;
    int nt = rem >> 9, l = (rem >> 3) & 63, jj = rem & 7;
    ((bf16*)(ws + OFF_WOUT))[id2] = (bf16)ldel(Wout, (size_t)(kt * 32 + ((l >> 4) << 3) + jj) * 256 + nt * 16 + (l & 15), fl);
  } else if (id < 13897728) {
    int pc = id - 13893632;
    ((float*)(ws + OFF_B0P))[pc] = ldel(b0, (pc & 3) * 1024 + (pc >> 2), fl);
  } else if (id < 13901824) {
    int pc = id - 13897728;
    ((float*)(ws + OFF_B1P))[pc] = ldel(b1, (pc & 3) * 1024 + (pc >> 2), fl);
  } else if (id < 13902080) {
    int pc = id - 13901824;
    ((float*)(ws + OFF_BOP))[pc] = ldel(bout, pc, fl);
  } else if (id < 22290688) {
    int id2 = id - 13902080;
    int t = id2 >> 14, rem = id2 & 16383;
    int mt = rem >> 12, rem2 = rem & 4095;
    int kt = rem2 >> 9, l = (rem2 >> 3) & 63, j = rem2 & 7;
    int b = mt * 16 + (l & 15);
    int v = kt * 32 + ((l >> 4) << 3) + j;
    ((bf16*)(ws + OFF_XP))[id2] = (bf16)ldel(x, ((size_t)b * 512 + t) * 256 + v, fl);
  }
}

// ---------------- initial h states + grid flags ----------------
__global__ __launch_bounds__(256) void init_state(const void* __restrict__ s0, const void* __restrict__ s1,
                                                  char* __restrict__ ws) {
  const int fl = *(const unsigned*)(ws + OFF_FLAG);
  int id = blockIdx.x * 256 + threadIdx.x;
  if (id < 65536) {
    int b = id >> 10, u = id & 1023;
    *(bf16*)(ws + OFF_H0PP + 131072 + hpack_off(b, u)) = (bf16)ldel(s0, b * 2048 + 1024 + u, fl);
  } else if (id < 131072) {
    int id2 = id - 65536; int b = id2 >> 10, u = id2 & 1023;
    *(bf16*)(ws + OFF_H1PP + hpack_off(b, u)) = (bf16)ldel(s1, b * 2048 + 1024 + u, fl);
  } else if (id < 131328) {
    ((unsigned*)(ws + OFF_FLAGS))[id - 131072] = 0u;
  }
}

// ---------------- per-wave worker: self-staged A slice, B in registers, no K-loop sync ----------------
// Wave W owns panel ktiles [18W, 18W+18): layer0 B-frags for kt<40, layer1 for kt>=8, WOUT for kt>=40.
// A panel ktiles: [0..7]=x(it), [8..39]=h0(it-1), [40..71]=h1(it-2).
// 9 chunks of 2 ktiles; private 3-buffer LDS ring; s_waitcnt vmcnt gating (16/8/0).
template<int W>
__device__ __forceinline__ void run_wave(char* smem, char* ws, void* outv, int fl, int lane,
                                         int cu, int nt, int mo, int dg,
                                         const void* s0, const void* s1) {
  constexpr int N0 = (W <= 1) ? 18 : (W == 2 ? 4 : 0);   // layer0 ktiles in slice
  constexpr int S1 = (W == 0) ? 8 : 0;                   // first kt_local with layer1
  constexpr int N1 = 18 - S1;
  constexpr int SP = (W == 2) ? 4 : 0;                   // first kt_local with WOUT
  constexpr int NP = (W == 2) ? 14 : (W == 3 ? 18 : 0);
  unsigned* flags = (unsigned*)(ws + OFF_FLAGS);
  unsigned* arr2 = (unsigned*)(smem + L_SYNC);
  char* ring = smem + L_A + W * 24576;

  bf16x8 b0reg[N0 > 0 ? N0 : 1], b1reg[N1], wreg[NP > 0 ? NP : 1];
#pragma unroll
  for (int i = 0; i < N0; ++i)
    b0reg[i] = *(const bf16x8*)(ws + OFF_W0P + ((size_t)cu * 40 + 18 * W + i) * 1024 + (size_t)lane * 16);
#pragma unroll
  for (int i = 0; i < N1; ++i)
    b1reg[i] = *(const bf16x8*)(ws + OFF_W1P + ((size_t)cu * 64 + (18 * W + S1 + i - 8)) * 1024 + (size_t)lane * 16);
#pragma unroll
  for (int i = 0; i < NP; ++i)
    wreg[i] = *(const bf16x8*)(ws + OFF_WOUT + ((size_t)((18 * W + SP + i - 40) * 16 + nt) * 64 + lane) * 16);

  const float bini0 = ((const float*)(ws + OFF_B0P))[cu * 16 + (lane & 15)];
  const float bini1 = ((const float*)(ws + OFF_B1P))[cu * 16 + (lane & 15)];
  const float boN = ((const float*)(ws + OFF_BOP))[nt * 16 + (lane & 15)];
  const int u0 = cu * 4 + ((lane & 15) >> 2);
  float c0reg[4], c1reg[4];
#pragma unroll
  for (int r = 0; r < 4; ++r) {
    int b = W * 16 + ((lane >> 4) << 2) + r;   // wave W owns m-tile W for pointwise/state
    c0reg[r] = ldel(s0, b * 2048 + u0, fl);
    c1reg[r] = ldel(s1, b * 2048 + u0, fl);
  }

  auto store_out = [&](size_t idx, float v) {
    if (fl) ((float*)outv)[idx] = v; else ((bf16*)outv)[idx] = (bf16)v;
  };

  for (int it = 0; it < 514; ++it) {
    const bool a0 = (it < 512);
    const bool a1 = (it >= 1 && it <= 512);
    const bool aP = (it >= 2 && ((it - 2) & 3) == dg);
    const int tt = (it < 512) ? it : 511;
    const char* xsrc  = ws + OFF_XP + (size_t)tt * 32768;
    const char* h0src = ws + OFF_H0PP + (size_t)((it + 1) & 1) * 131072;   // h0(it-1)
    const char* h1src = ws + OFF_H1PP + (size_t)((it + 1) & 1) * 131072;   // h1(it-2)

    // ---- grid wait: all CUs completed iter it-1 (proven r5 pattern) ----
    if (it >= 1) {
      unsigned tgt = (unsigned)it;
      bool rdy;
      do {
        int ok = 1;
#pragma unroll
        for (int i = 0; i < 4; ++i) {
          unsigned v = __hip_atomic_load(&flags[lane * 4 + i], __ATOMIC_RELAXED, __HIP_MEMORY_SCOPE_AGENT);
          ok &= (v >= tgt) ? 1 : 0;
        }
        rdy = __all(ok);
        if (!rdy) __builtin_amdgcn_s_sleep(1);
      } while (!rdy);
      __builtin_amdgcn_fence(__ATOMIC_ACQUIRE, "agent");
    }

    auto issue = [&](int j) {   // stage chunk j (ktiles 18W+2j, 18W+2j+1) into ring buf j%3
      char* buf = ring + (j % 3) * 8192;
#pragma unroll
      for (int kk = 0; kk < 2; ++kk) {
        int kt = 18 * W + j * 2 + kk;
#pragma unroll
        for (int m = 0; m < 4; ++m) {
          const char* src = (kt < 8)  ? xsrc  + (size_t)((m * 8 + kt) * 64 + lane) * 16
                          : (kt < 40) ? h0src + (size_t)((m * 32 + (kt - 8)) * 64 + lane) * 16
                                      : h1src + (size_t)((m * 32 + (kt - 40)) * 64 + lane) * 16;
          gl_lds16(buf + (size_t)((kk * 4 + m) * 1024) + (size_t)lane * 16, src);
        }
      }
    };

    issue(0); issue(1); issue(2);

    f32x4 acc0[4], acc1[4], accP;
#pragma unroll
    for (int m = 0; m < 4; ++m) {
#pragma unroll
      for (int r = 0; r < 4; ++r) { acc0[m][r] = 0.f; acc1[m][r] = 0.f; }
    }
#pragma unroll
    for (int r = 0; r < 4; ++r) accP[r] = 0.f;

#pragma unroll
    for (int i = 0; i < 9; ++i) {
      if (i < 7) waitv16(); else if (i == 7) waitv8(); else waitv0();
      const char* buf = ring + (i % 3) * 8192;
#pragma unroll
      for (int kk = 0; kk < 2; ++kk) {
        const int L = i * 2 + kk;
        bf16x8 fr[4];
#pragma unroll
        for (int m = 0; m < 4; ++m)
          fr[m] = *(const bf16x8*)(buf + (size_t)((kk * 4 + m) * 1024) + (size_t)lane * 16);
        if (L < N0 && a0) {
#pragma unroll
          for (int m = 0; m < 4; ++m)
            acc0[m] = __builtin_amdgcn_mfma_f32_16x16x32_bf16(fr[m], b0reg[L < N0 ? L : 0], acc0[m], 0, 0, 0);
        }
        if (L >= S1 && a1) {
#pragma unroll
          for (int m = 0; m < 4; ++m)
            acc1[m] = __builtin_amdgcn_mfma_f32_16x16x32_bf16(fr[m], b1reg[L >= S1 ? L - S1 : 0], acc1[m], 0, 0, 0);
        }
        if (NP > 0 && L >= SP && aP)
          accP = __builtin_amdgcn_mfma_f32_16x16x32_bf16(fr[mo], wreg[(NP > 0 && L >= SP) ? L - SP : 0], accP, 0, 0, 0);
      }
      __asm__ volatile("" ::: "memory");
      if (i + 3 <= 8) issue(i + 3);
    }

    // ---- cross-wave reduction (one barrier per iter; pipeline already drained) ----
#pragma unroll
    for (int m = 0; m < 4; ++m) {
      *(f32x4*)(smem + L_G0 + (size_t)((W * 4 + m) * 64 + lane) * 16) = acc0[m];
      *(f32x4*)(smem + L_G1 + (size_t)((W * 4 + m) * 64 + lane) * 16) = acc1[m];
    }
    *(f32x4*)(smem + L_GP + (size_t)(W * 64 + lane) * 16) = accP;
    __syncthreads();

    f32x4 g0 = *(const f32x4*)(smem + L_G0 + (size_t)((0 * 4 + W) * 64 + lane) * 16);
    f32x4 g1 = *(const f32x4*)(smem + L_G1 + (size_t)((0 * 4 + W) * 64 + lane) * 16);
#pragma unroll
    for (int w2 = 1; w2 < 4; ++w2) {
      f32x4 p0 = *(const f32x4*)(smem + L_G0 + (size_t)((w2 * 4 + W) * 64 + lane) * 16);
      f32x4 p1 = *(const f32x4*)(smem + L_G1 + (size_t)((w2 * 4 + W) * 64 + lane) * 16);
#pragma unroll
      for (int r = 0; r < 4; ++r) { g0[r] += p0[r]; g1[r] += p1[r]; }
    }

    // ---- pointwise for m-tile W (bias added ONCE, post-reduction) ----
    const int base = lane & 60;
    if (a0) {
      char* h0w = ws + OFF_H0PP + (size_t)(it & 1) * 131072;
#pragma unroll
      for (int r = 0; r < 4; ++r) {
        float z = g0[r] + bini0;
        float zi = scrub(__shfl(z, base + 0, 64), 80.f);
        float zj = scrub(__shfl(z, base + 1, 64), 80.f);
        float zf = scrub(__shfl(z, base + 2, 64), 80.f);
        float zo = scrub(__shfl(z, base + 3, 64), 80.f);
        float c = c0reg[r];
        c = c * sigm(zf + 1.0f) + sigm(zi) * tanh_(zj);
        c = scrub(c, 1000.f);
        float hh = tanh_(c) * sigm(zo);
        c0reg[r] = c;
        if ((lane & 3) == 0) {
          int b = W * 16 + ((lane >> 4) << 2) + r;
          *(bf16*)(h0w + hpack_off(b, u0)) = (bf16)hh;
          if (it == 511) { store_out(OUT_FS0 + b * 2048 + u0, c); store_out(OUT_FS0 + b * 2048 + 1024 + u0, hh); }
        }
      }
    }
    if (a1) {
      char* h1w = ws + OFF_H1PP + (size_t)(it & 1) * 131072;   // h1(it-1) -> slot it&1
#pragma unroll
      for (int r = 0; r < 4; ++r) {
        float z = g1[r] + bini1;
        float zi = scrub(__shfl(z, base + 0, 64), 80.f);
        float zj = scrub(__shfl(z, base + 1, 64), 80.f);
        float zf = scrub(__shfl(z, base + 2, 64), 80.f);
        float zo = scrub(__shfl(z, base + 3, 64), 80.f);
        float c = c1reg[r];
        c = c * sigm(zf + 1.0f) + sigm(zi) * tanh_(zj);
        c = scrub(c, 1000.f);
        float hh = tanh_(c) * sigm(zo);
        c1reg[r] = c;
        if ((lane & 3) == 0) {
          int b = W * 16 + ((lane >> 4) << 2) + r;
          *(bf16*)(h1w + hpack_off(b, u0)) = (bf16)hh;
          if (it == 512) { store_out(OUT_FS1 + b * 2048 + u0, c); store_out(OUT_FS1 + b * 2048 + 1024 + u0, hh); }
        }
      }
    }
    if (aP && W == mo) {   // outproj epilogue: sum 4 wave partials, write out[:, it-2, nt-tile]
      f32x4 s = *(const f32x4*)(smem + L_GP + (size_t)(0 * 64 + lane) * 16);
#pragma unroll
      for (int w2 = 1; w2 < 4; ++w2) {
        f32x4 pq = *(const f32x4*)(smem + L_GP + (size_t)(w2 * 64 + lane) * 16);
#pragma unroll
        for (int r = 0; r < 4; ++r) s[r] += pq[r];
      }
      int t = it - 2;
#pragma unroll
      for (int r = 0; r < 4; ++r) {
        int b = mo * 16 + ((lane >> 4) << 2) + r;
        store_out(((size_t)b * 512 + t) * 256 + nt * 16 + (lane & 15), s[r] + boN);
      }
    }

    // ---- grid arrival ----
    waitv0();   // this wave's global stores at coherence point of L2
    __hip_atomic_fetch_add(arr2, 1u, __ATOMIC_ACQ_REL, __HIP_MEMORY_SCOPE_WORKGROUP);
    if (W == 0) {
      while (__hip_atomic_load(arr2, __ATOMIC_ACQUIRE, __HIP_MEMORY_SCOPE_WORKGROUP) < (unsigned)(4 * it + 4))
        __builtin_amdgcn_s_sleep(1);
      __builtin_amdgcn_fence(__ATOMIC_RELEASE, "agent");   // L2 writeback of all waves' stores
      if (lane == 0)
        __hip_atomic_store(&flags[cu], (unsigned)(it + 1), __ATOMIC_RELAXED, __HIP_MEMORY_SCOPE_AGENT);
    }
  }
}

__global__ __launch_bounds__(256, 1) void recur_kernel(const void* __restrict__ s0, const void* __restrict__ s1,
                                                       char* __restrict__ ws, void* __restrict__ outv) {
  extern __shared__ char smem[];
  const int fl = *(const unsigned*)(ws + OFF_FLAG);
  const int tid = threadIdx.x, lane = tid & 63, w = tid >> 6;
  const int cu = blockIdx.x;
  const int nt = cu & 15, mo = (cu >> 4) & 3, dg = cu >> 6;

  if (tid == 0) *(unsigned*)(smem + L_SYNC) = 0u;
  __syncthreads();

  switch (w) {
    case 0: run_wave<0>(smem, ws, outv, fl, lane, cu, nt, mo, dg, s0, s1); break;
    case 1: run_wave<1>(smem, ws, outv, fl, lane, cu, nt, mo, dg, s0, s1); break;
    case 2: run_wave<2>(smem, ws, outv, fl, lane, cu, nt, mo, dg, s0, s1); break;
    default: run_wave<3>(smem, ws, outv, fl, lane, cu, nt, mo, dg, s0, s1); break;
  }
}

extern "C" void kernel_launch(void* const* d_in, const int* in_sizes, int n_in,
                              void* d_out, int out_size, void* d_ws, size_t ws_size,
                              hipStream_t stream) {
  const void* x    = d_in[0];
  const void* s0   = d_in[1];
  const void* s1   = d_in[2];
  const void* W0   = d_in[3];
  const void* b0   = d_in[4];
  const void* W1   = d_in[5];
  const void* b1   = d_in[6];
  const void* Wout = d_in[7];
  const void* bout = d_in[8];
  char* ws = (char*)d_ws;
  (void)in_sizes; (void)n_in; (void)out_size; (void)ws_size;

  hipFuncSetAttribute((const void*)recur_kernel, hipFuncAttributeMaxDynamicSharedMemorySize, LDS_TOT);

  hipLaunchKernelGGL(detect_kernel, dim3(1),     dim3(256), 0, stream, W0, ws);
  hipLaunchKernelGGL(prep_pack,     dim3(87073), dim3(256), 0, stream, x, W0, b0, W1, b1, Wout, bout, ws);
  hipLaunchKernelGGL(init_state,    dim3(513),   dim3(256), 0, stream, s0, s1, ws);
  hipLaunchKernelGGL(recur_kernel,  dim3(256),   dim3(256), LDS_TOT, stream, s0, s1, ws, d_out);
}

// Round 8
// 21072.899 us; speedup vs baseline: 1.7491x; 1.7491x over previous
//
#include <hip/hip_runtime.h>
#include <stdint.h>

typedef __bf16 bf16;
typedef __attribute__((ext_vector_type(8))) __bf16 bf16x8;
typedef __attribute__((ext_vector_type(4))) float f32x4;

// ---------------- workspace layout (bytes), total ~45.1 MB ----------------
#define OFF_W0P   0ull
#define SZ_W0P    10485760ull
#define OFF_W1P   (OFF_W0P + SZ_W0P)
#define SZ_W1P    16777216ull
#define OFF_WOUT  (OFF_W1P + SZ_W1P)
#define SZ_WOUT   524288ull
#define OFF_B0P   (OFF_WOUT + SZ_WOUT)      // f32 permuted b0 [4096]
#define OFF_B1P   (OFF_B0P + 16384ull)      // f32 permuted b1 [4096]
#define OFF_BOP   (OFF_B1P + 16384ull)      // f32 bout [256]
#define OFF_BAR   (OFF_BOP + 1024ull)       // monotonic barrier counter
#define OFF_FLAG  (OFF_BAR + 128ull)        // dtype flag: 1 = inputs are f32, 0 = bf16
#define OFF_H0PP  (OFF_BAR + 256ull)        // h0 ping-pong: 2 x 131072 (A-frag packed bf16)
#define OFF_H1PP  (OFF_H0PP + 262144ull)    // h1 ping-pong: 2 x 131072
#define OFF_XP    (OFF_H1PP + 262144ull)    // x repacked: [t 512][mt 4][kt 8][lane 64][8 bf16]
#define SZ_XP     16777216ull
#define OFF_FLAGS (OFF_XP + SZ_XP)          // (legacy flag array, zeroed, unused)
// end = 45,123,840 bytes

#define OUT_FS0   8388608
#define OUT_FS1   8519680

// LDS map (dynamic): A dbuf 2 x 49152 (chunk = 12 ktiles x 4 m x 1KB); reduce scratch after.
#define L_A     0
#define L_G0    98304    // acc0 partials: [w 4][m 4][lane 64] x 16B
#define L_G1    114688
#define L_GP    131072   // accP partials: [w 4][lane 64] x 16B
#define LDS_TOT 135168

typedef const __attribute__((address_space(1))) void gvoid_t;
typedef __attribute__((address_space(3))) void lvoid_t;

__device__ __forceinline__ void gl_lds16(void* lds, const void* g) {
  __builtin_amdgcn_global_load_lds((gvoid_t*)g, (lvoid_t*)lds, 16, 0, 0);
}

__device__ __forceinline__ size_t hpack_off(int b, int u) {
  return (size_t)((((b >> 4) * 32 + (u >> 5)) * 64 + ((b & 15) | (((u >> 3) & 3) << 4))) * 16 + ((u & 7) << 1));
}
__device__ __forceinline__ float sigm(float v) { return 1.0f / (1.0f + __expf(-v)); }
__device__ __forceinline__ float tanh_(float v) { return 2.0f / (1.0f + __expf(-2.0f * v)) - 1.0f; }
__device__ __forceinline__ float scrub(float v, float lim) { return fminf(fmaxf(v, -lim), lim); }
__device__ __forceinline__ float ldel(const void* p, size_t i, int fl) {
  return fl ? ((const float*)p)[i] : (float)((const bf16*)p)[i];
}

// ---------------- dtype detection ----------------
__global__ __launch_bounds__(256) void detect_kernel(const void* __restrict__ W0, char* __restrict__ ws) {
  __shared__ int cnt;
  if (threadIdx.x == 0) cnt = 0;
  __syncthreads();
  int local = 0;
  const unsigned* w = (const unsigned*)W0;
#pragma unroll
  for (int i = 0; i < 4; ++i) {
    unsigned e = (w[threadIdx.x * 4 + i] >> 7) & 0xFF;
    local += (e >= 0x68 && e <= 0x7E) ? 1 : 0;
  }
  atomicAdd(&cnt, local);
  __syncthreads();
  if (threadIdx.x == 0) *(unsigned*)(ws + OFF_FLAG) = (cnt < 512) ? 1u : 0u;
}

// ---------------- weight/x prep (proven round 4) ----------------
__global__ __launch_bounds__(256) void prep_pack(const void* __restrict__ x, const void* __restrict__ W0,
                                                 const void* __restrict__ b0, const void* __restrict__ W1,
                                                 const void* __restrict__ b1, const void* __restrict__ Wout,
                                                 const void* __restrict__ bout, char* __restrict__ ws) {
  const int fl = *(const unsigned*)(ws + OFF_FLAG);
  int id = blockIdx.x * 256 + threadIdx.x;
  if (id < 5242880) {
    int tile = id / 20480, rem = id % 20480;
    int kt = rem >> 9, l = (rem >> 3) & 63, jj = rem & 7;
    int k = kt * 32 + ((l >> 4) << 3) + jj;
    int pc = tile * 16 + (l & 15);
    ((bf16*)(ws + OFF_W0P))[id] = (bf16)ldel(W0, (size_t)k * 4096 + (pc & 3) * 1024 + (pc >> 2), fl);
  } else if (id < 13631488) {
    int id2 = id - 5242880;
    int tile = id2 >> 15, rem = id2 & 32767;
    int kt = rem >> 9, l = (rem >> 3) & 63, jj = rem & 7;
    int k = kt * 32 + ((l >> 4) << 3) + jj;
    int pc = tile * 16 + (l & 15);
    ((bf16*)(ws + OFF_W1P))[id2] = (bf16)ldel(W1, (size_t)k * 4096 + (pc & 3) * 1024 + (pc >> 2), fl);
  } else if (id < 13893632) {
    int id2 = id - 13631488;
    int kt = id2 / 8192, rem = id2 % 8192;
    int nt = rem >> 9, l = (rem >> 3) & 63, jj = rem & 7;
    ((bf16*)(ws + OFF_WOUT))[id2] = (bf16)ldel(Wout, (size_t)(kt * 32 + ((l >> 4) << 3) + jj) * 256 + nt * 16 + (l & 15), fl);
  } else if (id < 13897728) {
    int pc = id - 13893632;
    ((float*)(ws + OFF_B0P))[pc] = ldel(b0, (pc & 3) * 1024 + (pc >> 2), fl);
  } else if (id < 13901824) {
    int pc = id - 13897728;
    ((float*)(ws + OFF_B1P))[pc] = ldel(b1, (pc & 3) * 1024 + (pc >> 2), fl);
  } else if (id < 13902080) {
    int pc = id - 13901824;
    ((float*)(ws + OFF_BOP))[pc] = ldel(bout, pc, fl);
  } else if (id < 22290688) {
    int id2 = id - 13902080;
    int t = id2 >> 14, rem = id2 & 16383;
    int mt = rem >> 12, rem2 = rem & 4095;
    int kt = rem2 >> 9, l = (rem2 >> 3) & 63, j = rem2 & 7;
    int b = mt * 16 + (l & 15);
    int v = kt * 32 + ((l >> 4) << 3) + j;
    ((bf16*)(ws + OFF_XP))[id2] = (bf16)ldel(x, ((size_t)b * 512 + t) * 256 + v, fl);
  }
}

// ---------------- initial h states + barrier init ----------------
__global__ __launch_bounds__(256) void init_state(const void* __restrict__ s0, const void* __restrict__ s1,
                                                  char* __restrict__ ws) {
  const int fl = *(const unsigned*)(ws + OFF_FLAG);
  int id = blockIdx.x * 256 + threadIdx.x;
  if (id < 65536) {
    int b = id >> 10, u = id & 1023;
    *(bf16*)(ws + OFF_H0PP + 131072 + hpack_off(b, u)) = (bf16)ldel(s0, b * 2048 + 1024 + u, fl);
  } else if (id < 131072) {
    int id2 = id - 65536; int b = id2 >> 10, u = id2 & 1023;
    *(bf16*)(ws + OFF_H1PP + hpack_off(b, u)) = (bf16)ldel(s1, b * 2048 + 1024 + u, fl);
  } else if (id == 131072) {
    *(unsigned*)(ws + OFF_BAR) = 0u;
  } else if (id > 131072 && id < 131584) {
    ((unsigned*)(ws + OFF_FLAGS))[id - 131073] = 0u;
  }
}

// ---------------- persistent kernel v4: r4 structure + register B + 48KB chunks ----------------
// 256 WGs x 256 threads, 1 WG/CU. CU cu owns 16 permuted gate-cols of layer0/layer1 (tile cu)
// + outproj job (nt=cu&15, mo=(cu>>4)&3, dg=cu>>6).
// K-split by wave: wave w owns panel ktiles == w (mod 4). B-frags in registers:
//   b0reg[i] <- W0P ktile 4i+w (i<10), b1reg[i] <- W1P ktile 4i+w (i<16), wreg[i] <- WOUT ktile 4i+w (i<8).
// A panel (72 ktiles: [0..7]=x(it), [8..39]=h0(it-1), [40..71]=h1(it-2)) staged in 6 chunks of
// 12 ktiles (48KB), double-buffered; wave w stages m-tile w lines of each chunk (12 gl_lds/thread).
// For chunk c, j in 0..2: panel kt = 12c+4j+w, q=3c+j: b0 idx q (q<=9), b1 idx q-2 (q>=2), wout q-10 (q>=10).
// Cross-wave f32 LDS reduction; pointwise by wave w for m-tile w; r4 barrier verbatim.
__global__ __launch_bounds__(256, 1) void recur_kernel(const void* __restrict__ s0, const void* __restrict__ s1,
                                                       char* __restrict__ ws, void* __restrict__ outv) {
  extern __shared__ char smem[];
  const int fl = *(const unsigned*)(ws + OFF_FLAG);
  const int tid = threadIdx.x, lane = tid & 63, w = tid >> 6;
  const int cu = blockIdx.x;
  const int nt = cu & 15, mo = (cu >> 4) & 3, dg = cu >> 6;
  unsigned* bar = (unsigned*)(ws + OFF_BAR);

  auto store_out = [&](size_t idx, float v) {
    if (fl) ((float*)outv)[idx] = v; else ((bf16*)outv)[idx] = (bf16)v;
  };

  // ---- B fragments in registers ----
  bf16x8 b0reg[10], b1reg[16], wreg[8];
#pragma unroll
  for (int i = 0; i < 10; ++i)
    b0reg[i] = *(const bf16x8*)(ws + OFF_W0P + ((size_t)cu * 40 + 4 * i + w) * 1024 + (size_t)lane * 16);
#pragma unroll
  for (int i = 0; i < 16; ++i)
    b1reg[i] = *(const bf16x8*)(ws + OFF_W1P + ((size_t)cu * 64 + 4 * i + w) * 1024 + (size_t)lane * 16);
#pragma unroll
  for (int i = 0; i < 8; ++i)
    wreg[i] = *(const bf16x8*)(ws + OFF_WOUT + ((size_t)((4 * i + w) * 16 + nt) * 64 + lane) * 16);

  const float bini0 = ((const float*)(ws + OFF_B0P))[cu * 16 + (lane & 15)];
  const float bini1 = ((const float*)(ws + OFF_B1P))[cu * 16 + (lane & 15)];
  const float boN = ((const float*)(ws + OFF_BOP))[nt * 16 + (lane & 15)];
  const int u0 = cu * 4 + ((lane & 15) >> 2);
  float c0reg[4], c1reg[4];
#pragma unroll
  for (int r = 0; r < 4; ++r) {
    int b = w * 16 + ((lane >> 4) << 2) + r;   // wave w owns m-tile w for pointwise/state
    c0reg[r] = ldel(s0, b * 2048 + u0, fl);
    c1reg[r] = ldel(s1, b * 2048 + u0, fl);
  }

  for (int it = 0; it < 514; ++it) {
    const bool a0 = (it < 512);
    const bool a1 = (it >= 1 && it <= 512);
    const bool aP = (it >= 2 && ((it - 2) & 3) == dg);
    const bool st_h0 = (it <= 512);
    const bool st_h1 = (it >= 1);
    const char* xsrc  = ws + OFF_XP + (size_t)((it < 512) ? it : 511) * 32768;
    const char* h0src = ws + OFF_H0PP + (size_t)((it + 1) & 1) * 131072;   // h0(it-1)
    const char* h1src = ws + OFF_H1PP + (size_t)((it + 1) & 1) * 131072;   // h1(it-2)

    // stage chunk c (panel ktiles 12c..12c+11) into buffer c&1; wave w stages its m-tile-w lines
    auto stage = [&](int c) {
      char* buf = smem + (size_t)(c & 1) * 49152;
#pragma unroll
      for (int r = 0; r < 12; ++r) {
        int kt = 12 * c + r;
        const char* src; bool go;
        if (kt < 8)       { go = a0;    src = xsrc  + (size_t)((w * 8 + kt) * 64 + lane) * 16; }
        else if (kt < 40) { go = st_h0; src = h0src + (size_t)((w * 32 + (kt - 8)) * 64 + lane) * 16; }
        else              { go = st_h1; src = h1src + (size_t)((w * 32 + (kt - 40)) * 64 + lane) * 16; }
        if (go) gl_lds16(buf + (size_t)((r * 4 + w) * 1024) + (size_t)lane * 16, src);
      }
    };

    f32x4 acc0[4], acc1[4], accP;
#pragma unroll
    for (int m = 0; m < 4; ++m) {
#pragma unroll
      for (int r = 0; r < 4; ++r) { acc0[m][r] = 0.f; acc1[m][r] = 0.f; }
    }
#pragma unroll
    for (int r = 0; r < 4; ++r) accP[r] = 0.f;

    stage(0);
    __syncthreads();
    for (int c = 0; c < 6; ++c) {
      if (c < 5) stage(c + 1);
      const char* buf = smem + (size_t)(c & 1) * 49152;
#pragma unroll
      for (int j = 0; j < 3; ++j) {
        const int q = 3 * c + j;        // compile-time within unrolled c? c is runtime; q affine — ok
        const int lk = 4 * j + w;       // local ktile within chunk
        bf16x8 fr[4];
#pragma unroll
        for (int m = 0; m < 4; ++m)
          fr[m] = *(const bf16x8*)(buf + (size_t)((lk * 4 + m) * 1024) + (size_t)lane * 16);
        if (q <= 9 && a0) {
#pragma unroll
          for (int m = 0; m < 4; ++m)
            acc0[m] = __builtin_amdgcn_mfma_f32_16x16x32_bf16(fr[m], b0reg[q], acc0[m], 0, 0, 0);
        }
        if (q >= 2 && a1) {
#pragma unroll
          for (int m = 0; m < 4; ++m)
            acc1[m] = __builtin_amdgcn_mfma_f32_16x16x32_bf16(fr[m], b1reg[q - 2], acc1[m], 0, 0, 0);
        }
        if (q >= 10 && aP)
          accP = __builtin_amdgcn_mfma_f32_16x16x32_bf16(fr[mo], wreg[q - 10], accP, 0, 0, 0);
      }
      __syncthreads();
    }

    // ---- cross-wave reduction through LDS ----
#pragma unroll
    for (int m = 0; m < 4; ++m) {
      *(f32x4*)(smem + L_G0 + (size_t)((w * 4 + m) * 64 + lane) * 16) = acc0[m];
      *(f32x4*)(smem + L_G1 + (size_t)((w * 4 + m) * 64 + lane) * 16) = acc1[m];
    }
    *(f32x4*)(smem + L_GP + (size_t)(w * 64 + lane) * 16) = accP;
    __syncthreads();

    f32x4 g0 = *(const f32x4*)(smem + L_G0 + (size_t)((0 * 4 + w) * 64 + lane) * 16);
    f32x4 g1 = *(const f32x4*)(smem + L_G1 + (size_t)((0 * 4 + w) * 64 + lane) * 16);
#pragma unroll
    for (int w2 = 1; w2 < 4; ++w2) {
      f32x4 p0 = *(const f32x4*)(smem + L_G0 + (size_t)((w2 * 4 + w) * 64 + lane) * 16);
      f32x4 p1 = *(const f32x4*)(smem + L_G1 + (size_t)((w2 * 4 + w) * 64 + lane) * 16);
#pragma unroll
      for (int r = 0; r < 4; ++r) { g0[r] += p0[r]; g1[r] += p1[r]; }
    }

    // ---- pointwise for m-tile w (bias once, post-reduction) ----
    const int base = lane & 60;
    if (a0) {
      char* h0w = ws + OFF_H0PP + (size_t)(it & 1) * 131072;
#pragma unroll
      for (int r = 0; r < 4; ++r) {
        float z = g0[r] + bini0;
        float zi = scrub(__shfl(z, base + 0, 64), 80.f);
        float zj = scrub(__shfl(z, base + 1, 64), 80.f);
        float zf = scrub(__shfl(z, base + 2, 64), 80.f);
        float zo = scrub(__shfl(z, base + 3, 64), 80.f);
        float c = c0reg[r];
        c = c * sigm(zf + 1.0f) + sigm(zi) * tanh_(zj);
        c = scrub(c, 1000.f);
        float hh = tanh_(c) * sigm(zo);
        c0reg[r] = c;
        if ((lane & 3) == 0) {
          int b = w * 16 + ((lane >> 4) << 2) + r;
          *(bf16*)(h0w + hpack_off(b, u0)) = (bf16)hh;
          if (it == 511) { store_out(OUT_FS0 + b * 2048 + u0, c); store_out(OUT_FS0 + b * 2048 + 1024 + u0, hh); }
        }
      }
    }
    if (a1) {
      char* h1w = ws + OFF_H1PP + (size_t)(it & 1) * 131072;   // h1(it-1) -> slot it&1
#pragma unroll
      for (int r = 0; r < 4; ++r) {
        float z = g1[r] + bini1;
        float zi = scrub(__shfl(z, base + 0, 64), 80.f);
        float zj = scrub(__shfl(z, base + 1, 64), 80.f);
        float zf = scrub(__shfl(z, base + 2, 64), 80.f);
        float zo = scrub(__shfl(z, base + 3, 64), 80.f);
        float c = c1reg[r];
        c = c * sigm(zf + 1.0f) + sigm(zi) * tanh_(zj);
        c = scrub(c, 1000.f);
        float hh = tanh_(c) * sigm(zo);
        c1reg[r] = c;
        if ((lane & 3) == 0) {
          int b = w * 16 + ((lane >> 4) << 2) + r;
          *(bf16*)(h1w + hpack_off(b, u0)) = (bf16)hh;
          if (it == 512) { store_out(OUT_FS1 + b * 2048 + u0, c); store_out(OUT_FS1 + b * 2048 + 1024 + u0, hh); }
        }
      }
    }
    if (aP && w == mo) {   // outproj: sum 4 wave partials, write out[:, it-2, nt-tile]
      f32x4 s = *(const f32x4*)(smem + L_GP + (size_t)(0 * 64 + lane) * 16);
#pragma unroll
      for (int w2 = 1; w2 < 4; ++w2) {
        f32x4 pq = *(const f32x4*)(smem + L_GP + (size_t)(w2 * 64 + lane) * 16);
#pragma unroll
        for (int r = 0; r < 4; ++r) s[r] += pq[r];
      }
      int t = it - 2;
#pragma unroll
      for (int r = 0; r < 4; ++r) {
        int b = mo * 16 + ((lane >> 4) << 2) + r;
        store_out(((size_t)b * 512 + t) * 256 + nt * 16 + (lane & 15), s[r] + boN);
      }
    }

    // ---- grid barrier (r4 verbatim: monotonic counter, agent scope) ----
    __syncthreads();
    if (tid == 0) {
      __threadfence();
      __hip_atomic_fetch_add(bar, 1u, __ATOMIC_ACQ_REL, __HIP_MEMORY_SCOPE_AGENT);
      unsigned tgt = 256u * (unsigned)(it + 1);
      while (__hip_atomic_load(bar, __ATOMIC_ACQUIRE, __HIP_MEMORY_SCOPE_AGENT) < tgt) __builtin_amdgcn_s_sleep(8);
      __threadfence();
    }
    __syncthreads();
  }
}

extern "C" void kernel_launch(void* const* d_in, const int* in_sizes, int n_in,
                              void* d_out, int out_size, void* d_ws, size_t ws_size,
                              hipStream_t stream) {
  const void* x    = d_in[0];
  const void* s0   = d_in[1];
  const void* s1   = d_in[2];
  const void* W0   = d_in[3];
  const void* b0   = d_in[4];
  const void* W1   = d_in[5];
  const void* b1   = d_in[6];
  const void* Wout = d_in[7];
  const void* bout = d_in[8];
  char* ws = (char*)d_ws;
  (void)in_sizes; (void)n_in; (void)out_size; (void)ws_size;

  hipFuncSetAttribute((const void*)recur_kernel, hipFuncAttributeMaxDynamicSharedMemorySize, LDS_TOT);

  hipLaunchKernelGGL(detect_kernel, dim3(1),     dim3(256), 0, stream, W0, ws);
  hipLaunchKernelGGL(prep_pack,     dim3(87073), dim3(256), 0, stream, x, W0, b0, W1, b1, Wout, bout, ws);
  hipLaunchKernelGGL(init_state,    dim3(513),   dim3(256), 0, stream, s0, s1, ws);
  hipLaunchKernelGGL(recur_kernel,  dim3(256),   dim3(256), LDS_TOT, stream, s0, s1, ws, d_out);
}

// Round 9
// 18986.696 us; speedup vs baseline: 1.9413x; 1.1099x over previous
//
#include <hip/hip_runtime.h>
#include <stdint.h>

typedef __bf16 bf16;
typedef __attribute__((ext_vector_type(8))) __bf16 bf16x8;
typedef __attribute__((ext_vector_type(4))) float f32x4;

// ---------------- workspace layout (bytes), total ~45.1 MB ----------------
#define OFF_W0P   0ull
#define SZ_W0P    10485760ull
#define OFF_W1P   (OFF_W0P + SZ_W0P)
#define SZ_W1P    16777216ull
#define OFF_WOUT  (OFF_W1P + SZ_W1P)
#define SZ_WOUT   524288ull
#define OFF_B0P   (OFF_WOUT + SZ_WOUT)      // f32 permuted b0 [4096]
#define OFF_B1P   (OFF_B0P + 16384ull)      // f32 permuted b1 [4096]
#define OFF_BOP   (OFF_B1P + 16384ull)      // f32 bout [256]
#define OFF_BAR   (OFF_BOP + 1024ull)       // (legacy, zeroed, unused)
#define OFF_FLAG  (OFF_BAR + 128ull)        // dtype flag: 1 = inputs are f32, 0 = bf16
#define OFF_H0PP  (OFF_BAR + 256ull)        // h0 ping-pong: 2 x 131072 (A-frag packed bf16)
#define OFF_H1PP  (OFF_H0PP + 262144ull)    // h1 ping-pong: 2 x 131072
#define OFF_XP    (OFF_H1PP + 262144ull)    // x repacked: [t 512][mt 4][kt 8][lane 64][8 bf16]
#define SZ_XP     16777216ull
#define OFF_FLAGS (OFF_XP + SZ_XP)          // grid barrier flags: uint[256], monotonic
// end = 45,123,840 bytes

#define OUT_FS0   8388608
#define OUT_FS1   8519680

// LDS map (dynamic): A dbuf 2 x 49152 (chunk = 12 ktiles x 4 m x 1KB); reduce scratch after.
#define L_A     0
#define L_G0    98304    // acc0 partials: [w 4][m 4][lane 64] x 16B
#define L_G1    114688
#define L_GP    131072   // accP partials: [w 4][lane 64] x 16B
#define LDS_TOT 135168

typedef const __attribute__((address_space(1))) void gvoid_t;
typedef __attribute__((address_space(3))) void lvoid_t;

__device__ __forceinline__ void gl_lds16(void* lds, const void* g) {
  __builtin_amdgcn_global_load_lds((gvoid_t*)g, (lvoid_t*)lds, 16, 0, 0);
}
__device__ __forceinline__ void waitv0() { __asm__ volatile("s_waitcnt vmcnt(0)" ::: "memory"); }

__device__ __forceinline__ size_t hpack_off(int b, int u) {
  return (size_t)((((b >> 4) * 32 + (u >> 5)) * 64 + ((b & 15) | (((u >> 3) & 3) << 4))) * 16 + ((u & 7) << 1));
}
__device__ __forceinline__ float sigm(float v) { return 1.0f / (1.0f + __expf(-v)); }
__device__ __forceinline__ float tanh_(float v) { return 2.0f / (1.0f + __expf(-2.0f * v)) - 1.0f; }
__device__ __forceinline__ float scrub(float v, float lim) { return fminf(fmaxf(v, -lim), lim); }
__device__ __forceinline__ float ldel(const void* p, size_t i, int fl) {
  return fl ? ((const float*)p)[i] : (float)((const bf16*)p)[i];
}

// ---------------- dtype detection ----------------
__global__ __launch_bounds__(256) void detect_kernel(const void* __restrict__ W0, char* __restrict__ ws) {
  __shared__ int cnt;
  if (threadIdx.x == 0) cnt = 0;
  __syncthreads();
  int local = 0;
  const unsigned* w = (const unsigned*)W0;
#pragma unroll
  for (int i = 0; i < 4; ++i) {
    unsigned e = (w[threadIdx.x * 4 + i] >> 7) & 0xFF;
    local += (e >= 0x68 && e <= 0x7E) ? 1 : 0;
  }
  atomicAdd(&cnt, local);
  __syncthreads();
  if (threadIdx.x == 0) *(unsigned*)(ws + OFF_FLAG) = (cnt < 512) ? 1u : 0u;
}

// ---------------- weight/x prep (proven round 4) ----------------
__global__ __launch_bounds__(256) void prep_pack(const void* __restrict__ x, const void* __restrict__ W0,
                                                 const void* __restrict__ b0, const void* __restrict__ W1,
                                                 const void* __restrict__ b1, const void* __restrict__ Wout,
                                                 const void* __restrict__ bout, char* __restrict__ ws) {
  const int fl = *(const unsigned*)(ws + OFF_FLAG);
  int id = blockIdx.x * 256 + threadIdx.x;
  if (id < 5242880) {
    int tile = id / 20480, rem = id % 20480;
    int kt = rem >> 9, l = (rem >> 3) & 63, jj = rem & 7;
    int k = kt * 32 + ((l >> 4) << 3) + jj;
    int pc = tile * 16 + (l & 15);
    ((bf16*)(ws + OFF_W0P))[id] = (bf16)ldel(W0, (size_t)k * 4096 + (pc & 3) * 1024 + (pc >> 2), fl);
  } else if (id < 13631488) {
    int id2 = id - 5242880;
    int tile = id2 >> 15, rem = id2 & 32767;
    int kt = rem >> 9, l = (rem >> 3) & 63, jj = rem & 7;
    int k = kt * 32 + ((l >> 4) << 3) + jj;
    int pc = tile * 16 + (l & 15);
    ((bf16*)(ws + OFF_W1P))[id2] = (bf16)ldel(W1, (size_t)k * 4096 + (pc & 3) * 1024 + (pc >> 2), fl);
  } else if (id < 13893632) {
    int id2 = id - 13631488;
    int kt = id2 / 8192, rem = id2 % 8192;
    int nt = rem >> 9, l = (rem >> 3) & 63, jj = rem & 7;
    ((bf16*)(ws + OFF_WOUT))[id2] = (bf16)ldel(Wout, (size_t)(kt * 32 + ((l >> 4) << 3) + jj) * 256 + nt * 16 + (l & 15), fl);
  } else if (id < 13897728) {
    int pc = id - 13893632;
    ((float*)(ws + OFF_B0P))[pc] = ldel(b0, (pc & 3) * 1024 + (pc >> 2), fl);
  } else if (id < 13901824) {
    int pc = id - 13897728;
    ((float*)(ws + OFF_B1P))[pc] = ldel(b1, (pc & 3) * 1024 + (pc >> 2), fl);
  } else if (id < 13902080) {
    int pc = id - 13901824;
    ((float*)(ws + OFF_BOP))[pc] = ldel(bout, pc, fl);
  } else if (id < 22290688) {
    int id2 = id - 13902080;
    int t = id2 >> 14, rem = id2 & 16383;
    int mt = rem >> 12, rem2 = rem & 4095;
    int kt = rem2 >> 9, l = (rem2 >> 3) & 63, j = rem2 & 7;
    int b = mt * 16 + (l & 15);
    int v = kt * 32 + ((l >> 4) << 3) + j;
    ((bf16*)(ws + OFF_XP))[id2] = (bf16)ldel(x, ((size_t)b * 512 + t) * 256 + v, fl);
  }
}

// ---------------- initial h states + barrier init ----------------
__global__ __launch_bounds__(256) void init_state(const void* __restrict__ s0, const void* __restrict__ s1,
                                                  char* __restrict__ ws) {
  const int fl = *(const unsigned*)(ws + OFF_FLAG);
  int id = blockIdx.x * 256 + threadIdx.x;
  if (id < 65536) {
    int b = id >> 10, u = id & 1023;
    *(bf16*)(ws + OFF_H0PP + 131072 + hpack_off(b, u)) = (bf16)ldel(s0, b * 2048 + 1024 + u, fl);
  } else if (id < 131072) {
    int id2 = id - 65536; int b = id2 >> 10, u = id2 & 1023;
    *(bf16*)(ws + OFF_H1PP + hpack_off(b, u)) = (bf16)ldel(s1, b * 2048 + 1024 + u, fl);
  } else if (id == 131072) {
    *(unsigned*)(ws + OFF_BAR) = 0u;
  } else if (id > 131072 && id < 131584) {
    ((unsigned*)(ws + OFF_FLAGS))[id - 131073] = 0u;
  }
}

// ---------------- persistent kernel v5: r8 structure + invalidation-minimal flag barrier ----------------
// 256 WGs x 256 threads, 1 WG/CU. CU cu owns 16 permuted gate-cols of layer0/layer1 (tile cu)
// + outproj job (nt=cu&15, mo=(cu>>4)&3, dg=cu>>6).
// K-split by wave: wave w owns panel ktiles == w (mod 4); B-frags in registers (b0reg[q], b1reg[q-2],
// wreg[q-10] for q=3c+j). A panel (72 ktiles: [0..7]=x, [8..39]=h0(it-1), [40..71]=h1(it-2)) staged
// in 6 chunks of 48KB, double-buffered. Cross-wave f32 LDS reduction; pointwise by wave w (m-tile w).
// Barrier (the round-9 experiment): wait-at-top with RELAXED flag polls + ONE acquire fence per wave
// per iter; arrival = per-wave vmcnt(0) + syncthreads + tid0 release fence + RELAXED flag store.
// No agent-scope acquire executes during the staging window -> per-XCD L2 keeps the shared A panel.
__global__ __launch_bounds__(256, 1) void recur_kernel(const void* __restrict__ s0, const void* __restrict__ s1,
                                                       char* __restrict__ ws, void* __restrict__ outv) {
  extern __shared__ char smem[];
  const int fl = *(const unsigned*)(ws + OFF_FLAG);
  const int tid = threadIdx.x, lane = tid & 63, w = tid >> 6;
  const int cu = blockIdx.x;
  const int nt = cu & 15, mo = (cu >> 4) & 3, dg = cu >> 6;
  unsigned* flags = (unsigned*)(ws + OFF_FLAGS);

  auto store_out = [&](size_t idx, float v) {
    if (fl) ((float*)outv)[idx] = v; else ((bf16*)outv)[idx] = (bf16)v;
  };

  // ---- B fragments in registers ----
  bf16x8 b0reg[10], b1reg[16], wreg[8];
#pragma unroll
  for (int i = 0; i < 10; ++i)
    b0reg[i] = *(const bf16x8*)(ws + OFF_W0P + ((size_t)cu * 40 + 4 * i + w) * 1024 + (size_t)lane * 16);
#pragma unroll
  for (int i = 0; i < 16; ++i)
    b1reg[i] = *(const bf16x8*)(ws + OFF_W1P + ((size_t)cu * 64 + 4 * i + w) * 1024 + (size_t)lane * 16);
#pragma unroll
  for (int i = 0; i < 8; ++i)
    wreg[i] = *(const bf16x8*)(ws + OFF_WOUT + ((size_t)((4 * i + w) * 16 + nt) * 64 + lane) * 16);

  const float bini0 = ((const float*)(ws + OFF_B0P))[cu * 16 + (lane & 15)];
  const float bini1 = ((const float*)(ws + OFF_B1P))[cu * 16 + (lane & 15)];
  const float boN = ((const float*)(ws + OFF_BOP))[nt * 16 + (lane & 15)];
  const int u0 = cu * 4 + ((lane & 15) >> 2);
  float c0reg[4], c1reg[4];
#pragma unroll
  for (int r = 0; r < 4; ++r) {
    int b = w * 16 + ((lane >> 4) << 2) + r;   // wave w owns m-tile w for pointwise/state
    c0reg[r] = ldel(s0, b * 2048 + u0, fl);
    c1reg[r] = ldel(s1, b * 2048 + u0, fl);
  }

  for (int it = 0; it < 514; ++it) {
    const bool a0 = (it < 512);
    const bool a1 = (it >= 1 && it <= 512);
    const bool aP = (it >= 2 && ((it - 2) & 3) == dg);
    const bool st_h0 = (it <= 512);
    const bool st_h1 = (it >= 1);
    const char* xsrc  = ws + OFF_XP + (size_t)((it < 512) ? it : 511) * 32768;
    const char* h0src = ws + OFF_H0PP + (size_t)((it + 1) & 1) * 131072;   // h0(it-1)
    const char* h1src = ws + OFF_H1PP + (size_t)((it + 1) & 1) * 131072;   // h1(it-2)

    // ---- grid wait (top): all CUs completed iter it-1; RELAXED polls, ONE acquire fence ----
    if (it >= 1) {
      unsigned tgt = (unsigned)it;
      bool rdy;
      do {
        int ok = 1;
#pragma unroll
        for (int i = 0; i < 4; ++i) {
          unsigned v = __hip_atomic_load(&flags[lane * 4 + i], __ATOMIC_RELAXED, __HIP_MEMORY_SCOPE_AGENT);
          ok &= (v >= tgt) ? 1 : 0;
        }
        rdy = __all(ok);
        if (!rdy) __builtin_amdgcn_s_sleep(2);
      } while (!rdy);
      __builtin_amdgcn_fence(__ATOMIC_ACQUIRE, "agent");   // the only acquire this iter
    }

    // stage chunk c (panel ktiles 12c..12c+11) into buffer c&1; wave w stages its m-tile-w lines
    auto stage = [&](int c) {
      char* buf = smem + (size_t)(c & 1) * 49152;
#pragma unroll
      for (int r = 0; r < 12; ++r) {
        int kt = 12 * c + r;
        const char* src; bool go;
        if (kt < 8)       { go = a0;    src = xsrc  + (size_t)((w * 8 + kt) * 64 + lane) * 16; }
        else if (kt < 40) { go = st_h0; src = h0src + (size_t)((w * 32 + (kt - 8)) * 64 + lane) * 16; }
        else              { go = st_h1; src = h1src + (size_t)((w * 32 + (kt - 40)) * 64 + lane) * 16; }
        if (go) gl_lds16(buf + (size_t)((r * 4 + w) * 1024) + (size_t)lane * 16, src);
      }
    };

    f32x4 acc0[4], acc1[4], accP;
#pragma unroll
    for (int m = 0; m < 4; ++m) {
#pragma unroll
      for (int r = 0; r < 4; ++r) { acc0[m][r] = 0.f; acc1[m][r] = 0.f; }
    }
#pragma unroll
    for (int r = 0; r < 4; ++r) accP[r] = 0.f;

    stage(0);
    __syncthreads();
    for (int c = 0; c < 6; ++c) {
      if (c < 5) stage(c + 1);
      const char* buf = smem + (size_t)(c & 1) * 49152;
#pragma unroll
      for (int j = 0; j < 3; ++j) {
        const int q = 3 * c + j;
        const int lk = 4 * j + w;       // local ktile within chunk
        bf16x8 fr[4];
#pragma unroll
        for (int m = 0; m < 4; ++m)
          fr[m] = *(const bf16x8*)(buf + (size_t)((lk * 4 + m) * 1024) + (size_t)lane * 16);
        if (q <= 9 && a0) {
#pragma unroll
          for (int m = 0; m < 4; ++m)
            acc0[m] = __builtin_amdgcn_mfma_f32_16x16x32_bf16(fr[m], b0reg[q], acc0[m], 0, 0, 0);
        }
        if (q >= 2 && a1) {
#pragma unroll
          for (int m = 0; m < 4; ++m)
            acc1[m] = __builtin_amdgcn_mfma_f32_16x16x32_bf16(fr[m], b1reg[q - 2], acc1[m], 0, 0, 0);
        }
        if (q >= 10 && aP)
          accP = __builtin_amdgcn_mfma_f32_16x16x32_bf16(fr[mo], wreg[q - 10], accP, 0, 0, 0);
      }
      __syncthreads();
    }

    // ---- cross-wave reduction through LDS ----
#pragma unroll
    for (int m = 0; m < 4; ++m) {
      *(f32x4*)(smem + L_G0 + (size_t)((w * 4 + m) * 64 + lane) * 16) = acc0[m];
      *(f32x4*)(smem + L_G1 + (size_t)((w * 4 + m) * 64 + lane) * 16) = acc1[m];
    }
    *(f32x4*)(smem + L_GP + (size_t)(w * 64 + lane) * 16) = accP;
    __syncthreads();

    f32x4 g0 = *(const f32x4*)(smem + L_G0 + (size_t)((0 * 4 + w) * 64 + lane) * 16);
    f32x4 g1 = *(const f32x4*)(smem + L_G1 + (size_t)((0 * 4 + w) * 64 + lane) * 16);
#pragma unroll
    for (int w2 = 1; w2 < 4; ++w2) {
      f32x4 p0 = *(const f32x4*)(smem + L_G0 + (size_t)((w2 * 4 + w) * 64 + lane) * 16);
      f32x4 p1 = *(const f32x4*)(smem + L_G1 + (size_t)((w2 * 4 + w) * 64 + lane) * 16);
#pragma unroll
      for (int r = 0; r < 4; ++r) { g0[r] += p0[r]; g1[r] += p1[r]; }
    }

    // ---- pointwise for m-tile w (bias once, post-reduction) ----
    const int base = lane & 60;
    if (a0) {
      char* h0w = ws + OFF_H0PP + (size_t)(it & 1) * 131072;
#pragma unroll
      for (int r = 0; r < 4; ++r) {
        float z = g0[r] + bini0;
        float zi = scrub(__shfl(z, base + 0, 64), 80.f);
        float zj = scrub(__shfl(z, base + 1, 64), 80.f);
        float zf = scrub(__shfl(z, base + 2, 64), 80.f);
        float zo = scrub(__shfl(z, base + 3, 64), 80.f);
        float c = c0reg[r];
        c = c * sigm(zf + 1.0f) + sigm(zi) * tanh_(zj);
        c = scrub(c, 1000.f);
        float hh = tanh_(c) * sigm(zo);
        c0reg[r] = c;
        if ((lane & 3) == 0) {
          int b = w * 16 + ((lane >> 4) << 2) + r;
          *(bf16*)(h0w + hpack_off(b, u0)) = (bf16)hh;
          if (it == 511) { store_out(OUT_FS0 + b * 2048 + u0, c); store_out(OUT_FS0 + b * 2048 + 1024 + u0, hh); }
        }
      }
    }
    if (a1) {
      char* h1w = ws + OFF_H1PP + (size_t)(it & 1) * 131072;   // h1(it-1) -> slot it&1
#pragma unroll
      for (int r = 0; r < 4; ++r) {
        float z = g1[r] + bini1;
        float zi = scrub(__shfl(z, base + 0, 64), 80.f);
        float zj = scrub(__shfl(z, base + 1, 64), 80.f);
        float zf = scrub(__shfl(z, base + 2, 64), 80.f);
        float zo = scrub(__shfl(z, base + 3, 64), 80.f);
        float c = c1reg[r];
        c = c * sigm(zf + 1.0f) + sigm(zi) * tanh_(zj);
        c = scrub(c, 1000.f);
        float hh = tanh_(c) * sigm(zo);
        c1reg[r] = c;
        if ((lane & 3) == 0) {
          int b = w * 16 + ((lane >> 4) << 2) + r;
          *(bf16*)(h1w + hpack_off(b, u0)) = (bf16)hh;
          if (it == 512) { store_out(OUT_FS1 + b * 2048 + u0, c); store_out(OUT_FS1 + b * 2048 + 1024 + u0, hh); }
        }
      }
    }
    if (aP && w == mo) {   // outproj: sum 4 wave partials, write out[:, it-2, nt-tile]
      f32x4 s = *(const f32x4*)(smem + L_GP + (size_t)(0 * 64 + lane) * 16);
#pragma unroll
      for (int w2 = 1; w2 < 4; ++w2) {
        f32x4 pq = *(const f32x4*)(smem + L_GP + (size_t)(w2 * 64 + lane) * 16);
#pragma unroll
        for (int r = 0; r < 4; ++r) s[r] += pq[r];
      }
      int t = it - 2;
#pragma unroll
      for (int r = 0; r < 4; ++r) {
        int b = mo * 16 + ((lane >> 4) << 2) + r;
        store_out(((size_t)b * 512 + t) * 256 + nt * 16 + (lane & 15), s[r] + boN);
      }
    }

    // ---- grid arrival: per-wave store drain -> WG barrier -> single release fence + relaxed flag ----
    waitv0();          // this wave's global stores (h, out, fs) are at L2
    __syncthreads();   // all 4 waves drained
    if (tid == 0) {
      __builtin_amdgcn_fence(__ATOMIC_RELEASE, "agent");   // one wbl2: all this CU's dirty lines -> MALL
      __hip_atomic_store(&flags[cu], (unsigned)(it + 1), __ATOMIC_RELAXED, __HIP_MEMORY_SCOPE_AGENT);
    }
  }
}

extern "C" void kernel_launch(void* const* d_in, const int* in_sizes, int n_in,
                              void* d_out, int out_size, void* d_ws, size_t ws_size,
                              hipStream_t stream) {
  const void* x    = d_in[0];
  const void* s0   = d_in[1];
  const void* s1   = d_in[2];
  const void* W0   = d_in[3];
  const void* b0   = d_in[4];
  const void* W1   = d_in[5];
  const void* b1   = d_in[6];
  const void* Wout = d_in[7];
  const void* bout = d_in[8];
  char* ws = (char*)d_ws;
  (void)in_sizes; (void)n_in; (void)out_size; (void)ws_size;

  hipFuncSetAttribute((const void*)recur_kernel, hipFuncAttributeMaxDynamicSharedMemorySize, LDS_TOT);

  hipLaunchKernelGGL(detect_kernel, dim3(1),     dim3(256), 0, stream, W0, ws);
  hipLaunchKernelGGL(prep_pack,     dim3(87073), dim3(256), 0, stream, x, W0, b0, W1, b1, Wout, bout, ws);
  hipLaunchKernelGGL(init_state,    dim3(513),   dim3(256), 0, stream, s0, s1, ws);
  hipLaunchKernelGGL(recur_kernel,  dim3(256),   dim3(256), LDS_TOT, stream, s0, s1, ws, d_out);
}